// Round 5
// baseline (3786.638 us; speedup 1.0000x reference)
//
#include <hip/hip_runtime.h>
#include <math.h>

#define Bb 256
#define Tt 512
#define Ii 128
#define Hh 256
#define Ss 4
#define G4 1024  // 4*H gate rows

// Residency split for k_fused (per thread, 2 gate rows, 32 hh-chunks each):
//   row r0: wh0[32] in VGPRs (128 regs)
//   row r1: chunks 0..LCH-1 in LDS, LCH..LCH+VR1-1 in VGPRs, last 3 streamed (L1)
#define LCH 18   // LDS-resident r1 chunks -> 144 KiB
#define VR1 11   // VGPR-resident r1 chunks (44 regs); streamed = 32-LCH-VR1 = 3
#define TILE 8   // x-gate precompute tile (xg in 16 fp32 regs)

typedef _Float16 half2t __attribute__((ext_vector_type(2)));
union W16 { uint4 u; half2t h[4]; };
union CV8 { _Float16 h[4]; uint2 u; };

__device__ __forceinline__ float dot8(uint4 w, uint4 hv, float acc) {
  W16 a; a.u = w; W16 b; b.u = hv;
#if __has_builtin(__builtin_amdgcn_fdot2)
  acc = __builtin_amdgcn_fdot2(a.h[0], b.h[0], acc, false);
  acc = __builtin_amdgcn_fdot2(a.h[1], b.h[1], acc, false);
  acc = __builtin_amdgcn_fdot2(a.h[2], b.h[2], acc, false);
  acc = __builtin_amdgcn_fdot2(a.h[3], b.h[3], acc, false);
#else
#pragma unroll
  for (int k = 0; k < 4; k++)
    acc += (float)a.h[k].x * (float)b.h[k].x + (float)a.h[k].y * (float)b.h[k].y;
#endif
  return acc;
}

// ---------------- kernel 1: lengths[b] = max(sum(mask[b,:]), 1) ----------------
__global__ void k_len(const int* __restrict__ mask, int* __restrict__ len) {
  int b = blockIdx.x, tid = threadIdx.x;
  int c = (mask[b * Tt + tid] != 0) + (mask[b * Tt + 256 + tid] != 0);
#pragma unroll
  for (int off = 32; off > 0; off >>= 1) c += __shfl_down(c, off, 64);
  __shared__ int red[4];
  if ((tid & 63) == 0) red[tid >> 6] = c;
  __syncthreads();
  if (tid == 0) {
    int t = red[0] + red[1] + red[2] + red[3];
    len[b] = t < 1 ? 1 : t;
  }
}

// ---------------- kernel 2: weight transforms (fp32 -> packed fp16) ------------
// wt_hh16[(s*32+i8)*1024+o] = 8 halfs {W_hh[s][o][8i8..8i8+7]}
// wt_ih16[(s*16+i8)*1024+o] = 8 halfs {W_ih[s][o][8i8..8i8+7]}
__global__ void k_tr(const float* __restrict__ W_ih, const float* __restrict__ W_hh,
                     uint4* __restrict__ wt_hh16, uint4* __restrict__ wt_ih16) {
  int id = blockIdx.x * blockDim.x + threadIdx.x;
  const int NH16 = Ss * 32 * G4;  // 131072
  const int NI16 = Ss * 16 * G4;  // 65536
  if (id < NH16) {
    int o = id % G4, i8 = (id / G4) % 32, s = id / (G4 * 32);
    const float* src = W_hh + ((size_t)(s * G4 + o)) * Hh + 8 * i8;
    W16 w;
#pragma unroll
    for (int k = 0; k < 4; k++) {
      w.h[k].x = (_Float16)src[2 * k];
      w.h[k].y = (_Float16)src[2 * k + 1];
    }
    wt_hh16[id] = w.u;
  } else if (id < NH16 + NI16) {
    int id3 = id - NH16;
    int o = id3 % G4, i8 = (id3 / G4) % 16, s = id3 / (G4 * 16);
    const float* src = W_ih + ((size_t)(s * G4 + o)) * Ii + 8 * i8;
    W16 w;
#pragma unroll
    for (int k = 0; k < 4; k++) {
      w.h[k].x = (_Float16)src[2 * k];
      w.h[k].y = (_Float16)src[2 * k + 1];
    }
    wt_ih16[id3] = w.u;
  }
}

// ---------------- kernel 3: fused recurrence, weight-resident ------------------
// 512 threads = 8 waves, 1 block/CU (LDS-capped at 148.5 KiB -> 2 waves/EU).
// amdgpu_num_vgpr(256) overrides the backend's occupancy-driven VGPR target
// (rounds 3/4: scheduler targeted 128 regs despite the LDS cap, demoting the
// weight arrays to scratch -> 4.5 GB/dispatch of L2-thrashing traffic).
// Thread (u=tid&255, pr=tid>>8) owns rows r0 = u+pr*256 (i or f) and
// r1 = r0+512 (g or o). pr=1 sends sigmoid(f), sigmoid(o) via LDS; pr=0 keeps
// c and writes h. Per TILE steps: stage x->fp16 LDS, accumulate xg[2][TILE]
// (bias + W_ih@x) with W_ih streamed once per tile. Per step: 64 hh-dot8 from
// resident chunks; W_hh (re)loads only at <=4 block-uniform segment transitions.
__global__ __launch_bounds__(512)
__attribute__((amdgpu_num_vgpr(256))) void k_fused(
    const float* __restrict__ x, const uint4* __restrict__ wt_hh16,
    const uint4* __restrict__ wt_ih16, const float* __restrict__ b_ih,
    const float* __restrict__ b_hh, const int* __restrict__ len,
    float* __restrict__ out) {
  __shared__ __align__(16) uint4 lds_w[LCH * 512];   // 144 KiB, thread-private chunks
  __shared__ __align__(16) _Float16 xs[TILE * Ii];   // 2 KiB x tile (fp16)
  __shared__ __align__(16) _Float16 h_h[Hh];         // 512 B
  __shared__ float f_sh[Hh];
  __shared__ float o_sh[Hh];
  const int b = blockIdx.x;
  const int tid = threadIdx.x;
  const int u = tid & 255;
  const int pr = tid >> 8;
  const int r0 = u + pr * 256;
  const int r1 = r0 + 512;
  const int L = len[b];
  // segment boundaries: seg(t) = #{tb_i <= t}, tb_i = ceil(i*L/4)
  const int tb1 = (L + 3) >> 2;
  const int tb2 = (2 * L + 3) >> 2;
  const int tb3 = (3 * L + 3) >> 2;
  if (pr == 0) h_h[u] = (_Float16)0.f;
  float c = 0.f;
  float* outb = out + (size_t)b * Tt * Hh;
  float* lastb = out + (size_t)Bb * Tt * Hh + (size_t)b * Hh;
  const uint4* h4 = (const uint4*)h_h;
  const uint4* xs4 = (const uint4*)xs;
  uint4 wh0[32];   // r0 hh chunks, 128 VGPRs
  uint4 wr1[VR1];  // r1 hh chunks LCH..LCH+VR1-1, 44 VGPRs
  int s_cur = -1;
  float xg0[TILE], xg1[TILE];

  for (int t0 = 0; t0 < L; t0 += TILE) {  // t0 multiple of 8, t0 <= 504: no x overrun
    // ---- stage x[b, t0..t0+TILE) -> fp16 LDS ----
    if (tid < TILE * Ii / 4) {  // 256 threads, one float4 each
      float4 xf = ((const float4*)(x + ((size_t)b * Tt + t0) * Ii))[tid];
      CV8 cv;
      cv.h[0] = (_Float16)xf.x;
      cv.h[1] = (_Float16)xf.y;
      cv.h[2] = (_Float16)xf.z;
      cv.h[3] = (_Float16)xf.w;
      ((uint2*)xs)[tid] = cv.u;
    }
    __syncthreads();  // xs visible (also h_h init before first step)

    // ---- per-tile segment ids (block-uniform) ----
    int segv[TILE];
#pragma unroll
    for (int tt = 0; tt < TILE; tt++) {
      int t = t0 + tt;
      segv[tt] = (t >= tb1) + (t >= tb2) + (t >= tb3);
    }
    const int s_lo = segv[0];
    const int tlast = (t0 + TILE - 1 < L) ? (t0 + TILE - 1) : (L - 1);
    const int s_hi = (tlast >= tb1) + (tlast >= tb2) + (tlast >= tb3);

    // ---- phase A: xg[row][tt] = bias + W_ih[seg(t)]@x_t, accumulated in-place --
    for (int s = s_lo; s <= s_hi; s++) {  // <= 2 iterations (seg len >= 64 > TILE)
      float bias0 = b_ih[s * G4 + r0] + b_hh[s * G4 + r0];
      float bias1 = b_ih[s * G4 + r1] + b_hh[s * G4 + r1];
#pragma unroll
      for (int tt = 0; tt < TILE; tt++) {
        if (segv[tt] == s) { xg0[tt] = bias0; xg1[tt] = bias1; }
      }
      const uint4* wbi = wt_ih16 + ((size_t)s * 16) * G4;
#pragma unroll 2
      for (int i8 = 0; i8 < 16; i8++) {  // W_ih streamed once per tile, reused 8x
        uint4 w0 = wbi[(size_t)i8 * G4 + r0];
        uint4 w1 = wbi[(size_t)i8 * G4 + r1];
#pragma unroll
        for (int tt = 0; tt < TILE; tt++) {
          if (segv[tt] == s) {  // block-uniform per tt
            uint4 hv = xs4[tt * 16 + i8];  // wave-uniform LDS broadcast
            xg0[tt] = dot8(w0, hv, xg0[tt]);
            xg1[tt] = dot8(w1, hv, xg1[tt]);
          }
        }
      }
    }

    // ---- recurrence steps (fully unrolled: xg/wh0/wr1 statically indexed) ----
#pragma unroll
    for (int tt = 0; tt < TILE; tt++) {
      const int t = t0 + tt;
      if (t < L) {  // block-uniform
        const int s = segv[tt];
        if (s != s_cur) {  // block-uniform, <= 4 times total
          s_cur = s;
          const uint4* wb = wt_hh16 + (size_t)s * 32 * G4;
#pragma unroll
          for (int i8 = 0; i8 < 32; i8++) wh0[i8] = wb[(size_t)i8 * G4 + r0];
#pragma unroll
          for (int i8 = 0; i8 < LCH; i8++)
            lds_w[i8 * 512 + tid] = wb[(size_t)i8 * G4 + r1];  // own chunks only
#pragma unroll
          for (int k = 0; k < VR1; k++)
            wr1[k] = wb[(size_t)(LCH + k) * G4 + r1];
        }
        // streamed r1 chunks (same address each step; 24KB/CU -> L1-resident)
        const uint4* wbs = wt_hh16 + ((size_t)s_cur * 32) * G4 + r1;
        uint4 st0 = wbs[(size_t)(LCH + VR1 + 0) * G4];
        uint4 st1 = wbs[(size_t)(LCH + VR1 + 1) * G4];
        uint4 st2 = wbs[(size_t)(LCH + VR1 + 2) * G4];
        float a0 = xg0[tt], a1 = xg1[tt];
        float a0b = 0.f, a1b = 0.f;  // even/odd chains halve dependency depth
        __syncthreads();  // B1: prev h_h visible
#pragma unroll
        for (int i8 = 0; i8 < LCH; i8++) {
          uint4 hv = h4[i8];                 // wave-uniform broadcast
          uint4 wl = lds_w[i8 * 512 + tid];  // contiguous b128, conflict-free
          if (i8 & 1) { a0b = dot8(wh0[i8], hv, a0b); a1b = dot8(wl, hv, a1b); }
          else        { a0  = dot8(wh0[i8], hv, a0 ); a1  = dot8(wl, hv, a1 ); }
        }
#pragma unroll
        for (int i8 = LCH; i8 < LCH + VR1; i8++) {
          uint4 hv = h4[i8];
          if (i8 & 1) { a0b = dot8(wh0[i8], hv, a0b); a1b = dot8(wr1[i8 - LCH], hv, a1b); }
          else        { a0  = dot8(wh0[i8], hv, a0 ); a1  = dot8(wr1[i8 - LCH], hv, a1 ); }
        }
        {
          uint4 hv;
          hv = h4[LCH + VR1 + 0];
          a0  = dot8(wh0[LCH + VR1 + 0], hv, a0 );
          a1  = dot8(st0, hv, a1);
          hv = h4[LCH + VR1 + 1];
          a0b = dot8(wh0[LCH + VR1 + 1], hv, a0b);
          a1b = dot8(st1, hv, a1b);
          hv = h4[LCH + VR1 + 2];
          a0  = dot8(wh0[LCH + VR1 + 2], hv, a0 );
          a1  = dot8(st2, hv, a1);
        }
        a0 += a0b;
        a1 += a1b;
        if (pr == 1) {
          f_sh[u] = 1.f / (1.f + expf(-a0));
          o_sh[u] = 1.f / (1.f + expf(-a1));
        }
        __syncthreads();  // B2: h reads done; f/o visible
        if (pr == 0) {
          float ig = 1.f / (1.f + expf(-a0));
          float gg = tanhf(a1);
          c = f_sh[u] * c + ig * gg;
          float h = o_sh[u] * tanhf(c);
          h_h[u] = (_Float16)h;
          outb[(size_t)t * Hh + u] = h;
          if (t == L - 1) lastb[u] = h;
        }
      }
    }
  }
  // zero tail t >= L (all 512 threads, coalesced float4)
  {
    const int ztotal = (Tt - L) * (Hh / 4);
    float4* zb = (float4*)(outb + (size_t)L * Hh);
    float4 z; z.x = z.y = z.z = z.w = 0.f;
    for (int i = tid; i < ztotal; i += 512) zb[i] = z;
  }
}

extern "C" void kernel_launch(void* const* d_in, const int* in_sizes, int n_in,
                              void* d_out, int out_size, void* d_ws, size_t ws_size,
                              hipStream_t stream) {
  const float* x = (const float*)d_in[0];
  const int* mask = (const int*)d_in[1];
  const float* W_ih = (const float*)d_in[2];
  const float* W_hh = (const float*)d_in[3];
  const float* b_ih = (const float*)d_in[4];
  const float* b_hh = (const float*)d_in[5];
  float* out = (float*)d_out;
  char* ws = (char*)d_ws;

  const size_t HH16_OFF = 0;
  const size_t HH16_BYTES = (size_t)Ss * 32 * G4 * 16;  // 2 MiB
  const size_t IH16_OFF = HH16_OFF + HH16_BYTES;
  const size_t IH16_BYTES = (size_t)Ss * 16 * G4 * 16;  // 1 MiB
  const size_t LEN_OFF = IH16_OFF + IH16_BYTES;

  uint4* wt_hh16 = (uint4*)(ws + HH16_OFF);
  uint4* wt_ih16 = (uint4*)(ws + IH16_OFF);
  int* len = (int*)(ws + LEN_OFF);

  k_len<<<Bb, 256, 0, stream>>>(mask, len);
  k_tr<<<768, 256, 0, stream>>>(W_ih, W_hh, wt_hh16, wt_ih16);
  k_fused<<<Bb, 512, 0, stream>>>(x, wt_hh16, wt_ih16, b_ih, b_hh, len, out);
}

// Round 6
// 2385.913 us; speedup vs baseline: 1.5871x; 1.5871x over previous
//
#include <hip/hip_runtime.h>
#include <math.h>

#define Bb 256
#define Tt 512
#define Ii 128
#define Hh 256
#define Ss 4
#define G4 1024  // 4*H gate rows
#define NT 1024  // threads: ONE gate row per thread (fits the 128-VGPR budget)

// Per-row residency split (32 chunks of 16B = one W_hh row):
//   chunks 0..RL-1   -> LDS (thread-private, 144 KiB)
//   chunks RL..RL+RV-1 -> VGPRs (80 regs)
//   chunks RL+RV..31 -> streamed from L1/L2 each step (same addresses)
#define RL 9
#define RV 20
#define RS 3   // RL+RV+RS == 32
#define TILE 8 // x-gate precompute tile (xg/acc in 8 fp32 regs)

typedef _Float16 half2t __attribute__((ext_vector_type(2)));
union W16 { uint4 u; half2t h[4]; };
union CV8 { _Float16 h[4]; uint2 u; };

__device__ __forceinline__ float dot8(uint4 w, uint4 hv, float acc) {
  W16 a; a.u = w; W16 b; b.u = hv;
#if __has_builtin(__builtin_amdgcn_fdot2)
  acc = __builtin_amdgcn_fdot2(a.h[0], b.h[0], acc, false);
  acc = __builtin_amdgcn_fdot2(a.h[1], b.h[1], acc, false);
  acc = __builtin_amdgcn_fdot2(a.h[2], b.h[2], acc, false);
  acc = __builtin_amdgcn_fdot2(a.h[3], b.h[3], acc, false);
#else
#pragma unroll
  for (int k = 0; k < 4; k++)
    acc += (float)a.h[k].x * (float)b.h[k].x + (float)a.h[k].y * (float)b.h[k].y;
#endif
  return acc;
}

// ---------------- kernel 1: lengths[b] = max(sum(mask[b,:]), 1) ----------------
__global__ void k_len(const int* __restrict__ mask, int* __restrict__ len) {
  int b = blockIdx.x, tid = threadIdx.x;
  int c = (mask[b * Tt + tid] != 0) + (mask[b * Tt + 256 + tid] != 0);
#pragma unroll
  for (int off = 32; off > 0; off >>= 1) c += __shfl_down(c, off, 64);
  __shared__ int red[4];
  if ((tid & 63) == 0) red[tid >> 6] = c;
  __syncthreads();
  if (tid == 0) {
    int t = red[0] + red[1] + red[2] + red[3];
    len[b] = t < 1 ? 1 : t;
  }
}

// ---------------- kernel 2: weight transforms (fp32 -> packed fp16) ------------
// wt_hh16[(s*32+i8)*1024+o] = 8 halfs {W_hh[s][o][8i8..8i8+7]}
// wt_ih16[(s*16+i8)*1024+o] = 8 halfs {W_ih[s][o][8i8..8i8+7]}
__global__ void k_tr(const float* __restrict__ W_ih, const float* __restrict__ W_hh,
                     uint4* __restrict__ wt_hh16, uint4* __restrict__ wt_ih16) {
  int id = blockIdx.x * blockDim.x + threadIdx.x;
  const int NH16 = Ss * 32 * G4;  // 131072
  const int NI16 = Ss * 16 * G4;  // 65536
  if (id < NH16) {
    int o = id % G4, i8 = (id / G4) % 32, s = id / (G4 * 32);
    const float* src = W_hh + ((size_t)(s * G4 + o)) * Hh + 8 * i8;
    W16 w;
#pragma unroll
    for (int k = 0; k < 4; k++) {
      w.h[k].x = (_Float16)src[2 * k];
      w.h[k].y = (_Float16)src[2 * k + 1];
    }
    wt_hh16[id] = w.u;
  } else if (id < NH16 + NI16) {
    int id3 = id - NH16;
    int o = id3 % G4, i8 = (id3 / G4) % 16, s = id3 / (G4 * 16);
    const float* src = W_ih + ((size_t)(s * G4 + o)) * Ii + 8 * i8;
    W16 w;
#pragma unroll
    for (int k = 0; k < 4; k++) {
      w.h[k].x = (_Float16)src[2 * k];
      w.h[k].y = (_Float16)src[2 * k + 1];
    }
    wt_ih16[id3] = w.u;
  }
}

// ---------------- kernel 3: fused recurrence, 1 gate-row / thread --------------
// 1024 threads = 16 waves, 1 block/CU (150.5 KiB LDS), 4 waves/SIMD.
// The backend pins 512/1024-thread blocks to a 128-VGPR budget (rounds 3-5:
// every attribute attempt left VGPR_Count=128 with GB-scale scratch traffic),
// so the design is sized to FIT it: per-thread weight residency is one row =
// 32 chunks, split 20 VGPR + 9 LDS + 3 streamed. W_hh (re)loads only at <=4
// block-uniform segment transitions. Thread r in [0,1024) owns gate row r
// (i/f/g/o = r>>8); it writes its activated gate to gates[]; threads<256 then
// update c,h. Per TILE steps phase A computes xg[8] = bias + W_ih[seg]@x with
// W_ih streamed once per tile (reused 8x from LDS-staged fp16 x).
__global__ __launch_bounds__(NT) void k_fused(
    const float* __restrict__ x, const uint4* __restrict__ wt_hh16,
    const uint4* __restrict__ wt_ih16, const float* __restrict__ b_ih,
    const float* __restrict__ b_hh, const int* __restrict__ len,
    float* __restrict__ out) {
  __shared__ __align__(16) uint4 lds_w[RL * NT];     // 144 KiB, thread-private chunks
  __shared__ __align__(16) _Float16 xs[TILE * Ii];   // 2 KiB x tile (fp16)
  __shared__ __align__(16) _Float16 h_h[Hh];         // 512 B
  __shared__ float gates[NT];                        // 4 KiB activated gates
  const int b = blockIdx.x;
  const int tid = threadIdx.x;  // == gate row r
  const int u = tid & 255;
  const int L = len[b];
  // segment boundaries: seg(t) = #{tb_i <= t}, tb_i = ceil(i*L/4)
  const int tb1 = (L + 3) >> 2;
  const int tb2 = (2 * L + 3) >> 2;
  const int tb3 = (3 * L + 3) >> 2;
  if (tid < 256) h_h[tid] = (_Float16)0.f;
  float c = 0.f;  // live only in tid<256
  float* outb = out + (size_t)b * Tt * Hh;
  float* lastb = out + (size_t)Bb * Tt * Hh + (size_t)b * Hh;
  const uint4* h4 = (const uint4*)h_h;
  const uint4* xs4 = (const uint4*)xs;
  uint4 wv[RV];  // 80 VGPRs: chunks RL..RL+RV-1 of this thread's row
  int s_cur = -1;
  float xg[TILE];
  const bool is_g = (tid >= 512) && (tid < 768);  // wave-uniform (64-aligned)

  for (int t0 = 0; t0 < L; t0 += TILE) {  // t0 mult of 8, t0 <= 504: no x overrun
    // ---- stage x[b, t0..t0+TILE) -> fp16 LDS (256 threads, float4 each) ----
    if (tid < TILE * Ii / 4) {
      float4 xf = ((const float4*)(x + ((size_t)b * Tt + t0) * Ii))[tid];
      CV8 cv;
      cv.h[0] = (_Float16)xf.x;
      cv.h[1] = (_Float16)xf.y;
      cv.h[2] = (_Float16)xf.z;
      cv.h[3] = (_Float16)xf.w;
      ((uint2*)xs)[tid] = cv.u;
    }
    __syncthreads();  // xs visible (also h_h init before first step)

    // ---- per-tile segment ids (block-uniform) ----
    int segv[TILE];
#pragma unroll
    for (int tt = 0; tt < TILE; tt++) {
      int t = t0 + tt;
      segv[tt] = (t >= tb1) + (t >= tb2) + (t >= tb3);
    }
    const int s_lo = segv[0];
    const int tlast = (t0 + TILE - 1 < L) ? (t0 + TILE - 1) : (L - 1);
    const int s_hi = (tlast >= tb1) + (tlast >= tb2) + (tlast >= tb3);

    // ---- phase A: xg[tt] = bias + W_ih[seg(t)][row]@x_t (row = tid) ----------
    for (int s = s_lo; s <= s_hi; s++) {  // <= 2 iterations (seg len >= 64 > TILE)
      float acc[TILE];
#pragma unroll
      for (int tt = 0; tt < TILE; tt++) acc[tt] = 0.f;
      const uint4* wbi = wt_ih16 + ((size_t)s * 16) * G4 + tid;
#pragma unroll 2
      for (int i8 = 0; i8 < 16; i8++) {  // W_ih streamed once per tile, reused 8x
        uint4 w = wbi[(size_t)i8 * G4];
#pragma unroll
        for (int tt = 0; tt < TILE; tt++)
          acc[tt] = dot8(w, xs4[tt * 16 + i8], acc[tt]);
      }
      float bias = b_ih[s * G4 + tid] + b_hh[s * G4 + tid];
#pragma unroll
      for (int tt = 0; tt < TILE; tt++)
        if (segv[tt] == s) xg[tt] = acc[tt] + bias;
    }

    // ---- recurrence steps (fully unrolled: xg/wv statically indexed) ----
#pragma unroll
    for (int tt = 0; tt < TILE; tt++) {
      const int t = t0 + tt;
      if (t < L) {  // block-uniform
        const int s = segv[tt];
        if (s != s_cur) {  // block-uniform, <= 4 times total
          s_cur = s;
          const uint4* wb = wt_hh16 + (size_t)s * 32 * G4 + tid;
#pragma unroll
          for (int i8 = 0; i8 < RL; i8++)
            lds_w[i8 * NT + tid] = wb[(size_t)i8 * G4];  // own chunks only
#pragma unroll
          for (int k = 0; k < RV; k++) wv[k] = wb[(size_t)(RL + k) * G4];
        }
        // streamed chunks (same addresses each step; L1/L2-resident)
        const uint4* wbs = wt_hh16 + ((size_t)s_cur * 32) * G4 + tid;
        uint4 st0 = wbs[(size_t)(RL + RV + 0) * G4];
        uint4 st1 = wbs[(size_t)(RL + RV + 1) * G4];
        uint4 st2 = wbs[(size_t)(RL + RV + 2) * G4];
        float a = xg[tt], ab = 0.f;  // even/odd chains halve dependency depth
        __syncthreads();  // B1: prev h_h visible; prev gates[] reads done
#pragma unroll
        for (int i8 = 0; i8 < RL; i8++) {
          uint4 hv = h4[i8];                // wave-uniform broadcast
          uint4 wl = lds_w[i8 * NT + tid];  // contiguous b128, conflict-free
          if (i8 & 1) ab = dot8(wl, hv, ab);
          else        a  = dot8(wl, hv, a );
        }
#pragma unroll
        for (int k = 0; k < RV; k++) {
          uint4 hv = h4[RL + k];
          if ((RL + k) & 1) ab = dot8(wv[k], hv, ab);
          else              a  = dot8(wv[k], hv, a );
        }
        {
          uint4 hv;
          hv = h4[RL + RV + 0];
          a  = dot8(st0, hv, a);
          hv = h4[RL + RV + 1];
          ab = dot8(st1, hv, ab);
          hv = h4[RL + RV + 2];
          a  = dot8(st2, hv, a);
        }
        a += ab;
        // activated gate: tanh for g-rows (waves 8..11), sigmoid otherwise
        gates[tid] = is_g ? tanhf(a) : 1.f / (1.f + expf(-a));
        __syncthreads();  // B2: h reads done; gates visible
        if (tid < 256) {
          float ig = gates[u];
          float fg = gates[u + 256];
          float gg = gates[u + 512];
          float og = gates[u + 768];
          c = fg * c + ig * gg;
          float h = og * tanhf(c);
          h_h[u] = (_Float16)h;
          outb[(size_t)t * Hh + u] = h;
          if (t == L - 1) lastb[u] = h;
        }
      }
    }
  }
  // zero tail t >= L (all 1024 threads, coalesced float4)
  {
    const int ztotal = (Tt - L) * (Hh / 4);
    float4* zb = (float4*)(outb + (size_t)L * Hh);
    float4 z; z.x = z.y = z.z = z.w = 0.f;
    for (int i = tid; i < ztotal; i += NT) zb[i] = z;
  }
}

extern "C" void kernel_launch(void* const* d_in, const int* in_sizes, int n_in,
                              void* d_out, int out_size, void* d_ws, size_t ws_size,
                              hipStream_t stream) {
  const float* x = (const float*)d_in[0];
  const int* mask = (const int*)d_in[1];
  const float* W_ih = (const float*)d_in[2];
  const float* W_hh = (const float*)d_in[3];
  const float* b_ih = (const float*)d_in[4];
  const float* b_hh = (const float*)d_in[5];
  float* out = (float*)d_out;
  char* ws = (char*)d_ws;

  const size_t HH16_OFF = 0;
  const size_t HH16_BYTES = (size_t)Ss * 32 * G4 * 16;  // 2 MiB
  const size_t IH16_OFF = HH16_OFF + HH16_BYTES;
  const size_t IH16_BYTES = (size_t)Ss * 16 * G4 * 16;  // 1 MiB
  const size_t LEN_OFF = IH16_OFF + IH16_BYTES;

  uint4* wt_hh16 = (uint4*)(ws + HH16_OFF);
  uint4* wt_ih16 = (uint4*)(ws + IH16_OFF);
  int* len = (int*)(ws + LEN_OFF);

  k_len<<<Bb, 256, 0, stream>>>(mask, len);
  k_tr<<<768, 256, 0, stream>>>(W_ih, W_hh, wt_hh16, wt_ih16);
  k_fused<<<Bb, NT, 0, stream>>>(x, wt_hh16, wt_ih16, b_ih, b_hh, len, out);
}

// Round 7
// 2143.148 us; speedup vs baseline: 1.7669x; 1.1133x over previous
//
#include <hip/hip_runtime.h>
#include <math.h>

#define Bb 256
#define Tt 512
#define Ii 128
#define Hh 256
#define Ss 4
#define G4 1024  // 4*H gate rows

// The gfx950 backend pins the per-thread VGPR budget to 65536/blockDim
// (measured: 512thr->128, 1024thr->64; no attribute overrides it). Design to
// FIT 128 regs at 512 threads and stream the rest of W_hh from L2:
//   r0: LDS c0..9 | w0v[6]=c10..15 | streamed c16..31 (16)
//   r1: LDS c0..8 | w1v[4]=c9..12  | streamed c13..31 (19)
#define TILE 8  // x-gate precompute tile (xg in 16 fp32 regs)

typedef _Float16 half2t __attribute__((ext_vector_type(2)));
union W16 { uint4 u; half2t h[4]; };
union CV8 { _Float16 h[4]; uint2 u; };

__device__ __forceinline__ float dot8(uint4 w, uint4 hv, float acc) {
  W16 a; a.u = w; W16 b; b.u = hv;
#if __has_builtin(__builtin_amdgcn_fdot2)
  acc = __builtin_amdgcn_fdot2(a.h[0], b.h[0], acc, false);
  acc = __builtin_amdgcn_fdot2(a.h[1], b.h[1], acc, false);
  acc = __builtin_amdgcn_fdot2(a.h[2], b.h[2], acc, false);
  acc = __builtin_amdgcn_fdot2(a.h[3], b.h[3], acc, false);
#else
#pragma unroll
  for (int k = 0; k < 4; k++)
    acc += (float)a.h[k].x * (float)b.h[k].x + (float)a.h[k].y * (float)b.h[k].y;
#endif
  return acc;
}

// ---------------- kernel 1: lengths[b] = max(sum(mask[b,:]), 1) ----------------
__global__ void k_len(const int* __restrict__ mask, int* __restrict__ len) {
  int b = blockIdx.x, tid = threadIdx.x;
  int c = (mask[b * Tt + tid] != 0) + (mask[b * Tt + 256 + tid] != 0);
#pragma unroll
  for (int off = 32; off > 0; off >>= 1) c += __shfl_down(c, off, 64);
  __shared__ int red[4];
  if ((tid & 63) == 0) red[tid >> 6] = c;
  __syncthreads();
  if (tid == 0) {
    int t = red[0] + red[1] + red[2] + red[3];
    len[b] = t < 1 ? 1 : t;
  }
}

// ---------------- kernel 2: weight transforms (fp32 -> packed fp16) ------------
// wt_hh16[(s*32+i8)*1024+o] = 8 halfs {W_hh[s][o][8i8..8i8+7]}
// wt_ih16[(s*16+i8)*1024+o] = 8 halfs {W_ih[s][o][8i8..8i8+7]}
__global__ void k_tr(const float* __restrict__ W_ih, const float* __restrict__ W_hh,
                     uint4* __restrict__ wt_hh16, uint4* __restrict__ wt_ih16) {
  int id = blockIdx.x * blockDim.x + threadIdx.x;
  const int NH16 = Ss * 32 * G4;  // 131072
  const int NI16 = Ss * 16 * G4;  // 65536
  if (id < NH16) {
    int o = id % G4, i8 = (id / G4) % 32, s = id / (G4 * 32);
    const float* src = W_hh + ((size_t)(s * G4 + o)) * Hh + 8 * i8;
    W16 w;
#pragma unroll
    for (int k = 0; k < 4; k++) {
      w.h[k].x = (_Float16)src[2 * k];
      w.h[k].y = (_Float16)src[2 * k + 1];
    }
    wt_hh16[id] = w.u;
  } else if (id < NH16 + NI16) {
    int id3 = id - NH16;
    int o = id3 % G4, i8 = (id3 / G4) % 16, s = id3 / (G4 * 16);
    const float* src = W_ih + ((size_t)(s * G4 + o)) * Ii + 8 * i8;
    W16 w;
#pragma unroll
    for (int k = 0; k < 4; k++) {
      w.h[k].x = (_Float16)src[2 * k];
      w.h[k].y = (_Float16)src[2 * k + 1];
    }
    wt_ih16[id3] = w.u;
  }
}

// ---------------- kernel 3: fused recurrence, resident + L2-streamed -----------
// 512 threads = 8 waves, 1 block/CU (160 KiB LDS). Thread (u=tid&255, pr=tid>>8)
// owns rows r0=u+pr*256 (i or f) and r1=r0+512 (g or o). pr=1 sends sigmoid(f),
// sigmoid(o) via LDS; pr=0 keeps c and writes h. Per TILE steps: stage x->fp16
// LDS, compute xg[2][TILE] with W_ih streamed once per tile. Per step: 64 hh
// dot8 = 19 LDS-resident + 10 VGPR-resident + 33 streamed-from-L2 chunks
// (wt_hh16 is 2 MiB -> XCD-L2-resident; issue ladder keeps <=13 loads in
// flight so peak pressure stays under the 128-reg budget).
__global__ __launch_bounds__(512) void k_fused(
    const float* __restrict__ x, const uint4* __restrict__ wt_hh16,
    const uint4* __restrict__ wt_ih16, const float* __restrict__ b_ih,
    const float* __restrict__ b_hh, const int* __restrict__ len,
    float* __restrict__ out) {
  __shared__ __align__(16) uint4 lds_w[19 * 512];   // 152 KiB: L0..9=r0 c0..9, L10..18=r1 c0..8
  __shared__ __align__(16) _Float16 xs[TILE * Ii];  // 2 KiB x tile (fp16)
  __shared__ __align__(16) _Float16 h_h[Hh];        // 512 B
  __shared__ float f_sh[Hh];
  __shared__ float o_sh[Hh];
  const int b = blockIdx.x;
  const int tid = threadIdx.x;
  const int u = tid & 255;
  const int pr = tid >> 8;
  const int r0 = u + pr * 256;
  const int r1 = r0 + 512;
  const int L = len[b];
  // segment boundaries: seg(t) = #{tb_i <= t}, tb_i = ceil(i*L/4)
  const int tb1 = (L + 3) >> 2;
  const int tb2 = (2 * L + 3) >> 2;
  const int tb3 = (3 * L + 3) >> 2;
  if (pr == 0) h_h[u] = (_Float16)0.f;
  float c = 0.f;
  float* outb = out + (size_t)b * Tt * Hh;
  float* lastb = out + (size_t)Bb * Tt * Hh + (size_t)b * Hh;
  const uint4* h4 = (const uint4*)h_h;
  const uint4* xs4 = (const uint4*)xs;
  uint4 w0v[6];  // r0 chunks 10..15 (24 regs)
  uint4 w1v[4];  // r1 chunks 9..12  (16 regs)
  int s_cur = -1;
  float xg0[TILE], xg1[TILE];

  for (int t0 = 0; t0 < L; t0 += TILE) {  // t0 mult of 8, t0 <= 504: no x overrun
    // ---- stage x[b, t0..t0+TILE) -> fp16 LDS (256 threads, float4 each) ----
    if (tid < TILE * Ii / 4) {
      float4 xf = ((const float4*)(x + ((size_t)b * Tt + t0) * Ii))[tid];
      CV8 cv;
      cv.h[0] = (_Float16)xf.x;
      cv.h[1] = (_Float16)xf.y;
      cv.h[2] = (_Float16)xf.z;
      cv.h[3] = (_Float16)xf.w;
      ((uint2*)xs)[tid] = cv.u;
    }
    __syncthreads();  // xs visible (also h_h init before first step)

    // ---- per-tile segment ids (block-uniform) ----
    int segv[TILE];
#pragma unroll
    for (int tt = 0; tt < TILE; tt++) {
      int t = t0 + tt;
      segv[tt] = (t >= tb1) + (t >= tb2) + (t >= tb3);
    }
    const int s_lo = segv[0];
    const int tlast = (t0 + TILE - 1 < L) ? (t0 + TILE - 1) : (L - 1);
    const int s_hi = (tlast >= tb1) + (tlast >= tb2) + (tlast >= tb3);

    // ---- phase A (merged rows): xg[row][tt] = W_ih[seg(t)]@x_t + bias ----------
    for (int s = s_lo; s <= s_hi; s++) {  // <= 2 iterations
      float acc0[TILE], acc1[TILE];
#pragma unroll
      for (int tt = 0; tt < TILE; tt++) { acc0[tt] = 0.f; acc1[tt] = 0.f; }
      const uint4* wbi = wt_ih16 + ((size_t)s * 16) * G4;
#pragma unroll 2
      for (int i8 = 0; i8 < 16; i8++) {  // W_ih streamed once per tile, reused 8x
        uint4 w0 = wbi[(size_t)i8 * G4 + r0];
        uint4 w1 = wbi[(size_t)i8 * G4 + r1];
#pragma unroll
        for (int tt = 0; tt < TILE; tt++) {
          uint4 hv = xs4[tt * 16 + i8];  // wave-uniform LDS broadcast, shared rows
          acc0[tt] = dot8(w0, hv, acc0[tt]);
          acc1[tt] = dot8(w1, hv, acc1[tt]);
        }
      }
      float bias0 = b_ih[s * G4 + r0] + b_hh[s * G4 + r0];
      float bias1 = b_ih[s * G4 + r1] + b_hh[s * G4 + r1];
#pragma unroll
      for (int tt = 0; tt < TILE; tt++) {
        if (segv[tt] == s) {
          xg0[tt] = acc0[tt] + bias0;
          xg1[tt] = acc1[tt] + bias1;
        }
      }
    }

    // ---- recurrence steps (fully unrolled; all arrays statically indexed) ----
#pragma unroll
    for (int tt = 0; tt < TILE; tt++) {
      const int t = t0 + tt;
      if (t < L) {  // block-uniform
        const int s = segv[tt];
        if (s != s_cur) {  // block-uniform, <= 4 times total
          s_cur = s;
          const uint4* wb0 = wt_hh16 + (size_t)s * 32 * G4 + r0;
          const uint4* wb1 = wt_hh16 + (size_t)s * 32 * G4 + r1;
#pragma unroll
          for (int j = 0; j < 10; j++) lds_w[j * 512 + tid] = wb0[(size_t)j * G4];
#pragma unroll
          for (int j = 0; j < 9; j++)
            lds_w[(10 + j) * 512 + tid] = wb1[(size_t)j * G4];
#pragma unroll
          for (int k = 0; k < 6; k++) w0v[k] = wb0[(size_t)(10 + k) * G4];
#pragma unroll
          for (int k = 0; k < 4; k++) w1v[k] = wb1[(size_t)(9 + k) * G4];
        }
        // streamed chunk bases (L2-resident table; addresses fixed per segment)
        const uint4* wbs0 = wt_hh16 + (size_t)s_cur * 32 * G4 + r0;  // sA[k]=c16+k
        const uint4* wbs1 = wt_hh16 + (size_t)s_cur * 32 * G4 + r1;  // sB[k]=c13+k
        uint4 sA[16], sB[19];
        // pre-barrier issue group (fills during barrier wait): 6 in flight
        sB[0] = wbs1[(size_t)13 * G4];
        sB[1] = wbs1[(size_t)14 * G4];
        sB[2] = wbs1[(size_t)15 * G4];
        sB[3] = wbs1[(size_t)16 * G4];
        sA[0] = wbs0[(size_t)16 * G4];
        sA[1] = wbs0[(size_t)17 * G4];
        float a0 = xg0[tt], a1 = xg1[tt];
        float a0b = 0.f, a1b = 0.f;  // even/odd chains halve dependency depth
        __syncthreads();  // B1: prev h_h visible
#pragma unroll
        for (int i8 = 0; i8 < 32; i8++) {
          // issue ladder (i8 is an unroll constant -> all folds; <=13 in flight)
          if (i8 == 2) sB[4] = wbs1[(size_t)17 * G4];
          if (i8 == 5) sB[5] = wbs1[(size_t)18 * G4];
          if (i8 == 8) sB[6] = wbs1[(size_t)19 * G4];
          if (i8 == 11) sB[7] = wbs1[(size_t)20 * G4];
          if (i8 >= 13 && i8 <= 23) {  // two issues per consuming slot
            sB[i8 - 5] = wbs1[(size_t)(i8 + 8) * G4];   // sB[8..18] = c21..31
            if (i8 >= 14) sA[i8 - 12] = wbs0[(size_t)(i8 + 4) * G4];  // sA[2..11]=c18..27
          }
          if (i8 == 24) sA[12] = wbs0[(size_t)28 * G4];
          if (i8 == 25) sA[13] = wbs0[(size_t)29 * G4];
          if (i8 == 26) sA[14] = wbs0[(size_t)30 * G4];
          if (i8 == 27) sA[15] = wbs0[(size_t)31 * G4];
          uint4 hv = h4[i8];  // wave-uniform LDS broadcast
          uint4 wA = (i8 < 10) ? lds_w[i8 * 512 + tid]
                   : (i8 < 16) ? w0v[i8 - 10] : sA[i8 - 16];
          uint4 wB = (i8 < 9) ? lds_w[(10 + i8) * 512 + tid]
                   : (i8 < 13) ? w1v[i8 - 9] : sB[i8 - 13];
          if (i8 & 1) { a0b = dot8(wA, hv, a0b); a1b = dot8(wB, hv, a1b); }
          else        { a0  = dot8(wA, hv, a0 ); a1  = dot8(wB, hv, a1 ); }
        }
        a0 += a0b;
        a1 += a1b;
        if (pr == 1) {
          f_sh[u] = 1.f / (1.f + expf(-a0));
          o_sh[u] = 1.f / (1.f + expf(-a1));
        }
        __syncthreads();  // B2: h reads done; f/o visible
        if (pr == 0) {
          float ig = 1.f / (1.f + expf(-a0));
          float gg = tanhf(a1);
          c = f_sh[u] * c + ig * gg;
          float h = o_sh[u] * tanhf(c);
          h_h[u] = (_Float16)h;
          outb[(size_t)t * Hh + u] = h;
          if (t == L - 1) lastb[u] = h;
        }
      }
    }
  }
  // zero tail t >= L (all 512 threads, coalesced float4)
  {
    const int ztotal = (Tt - L) * (Hh / 4);
    float4* zb = (float4*)(outb + (size_t)L * Hh);
    float4 z; z.x = z.y = z.z = z.w = 0.f;
    for (int i = tid; i < ztotal; i += 512) zb[i] = z;
  }
}

extern "C" void kernel_launch(void* const* d_in, const int* in_sizes, int n_in,
                              void* d_out, int out_size, void* d_ws, size_t ws_size,
                              hipStream_t stream) {
  const float* x = (const float*)d_in[0];
  const int* mask = (const int*)d_in[1];
  const float* W_ih = (const float*)d_in[2];
  const float* W_hh = (const float*)d_in[3];
  const float* b_ih = (const float*)d_in[4];
  const float* b_hh = (const float*)d_in[5];
  float* out = (float*)d_out;
  char* ws = (char*)d_ws;

  const size_t HH16_OFF = 0;
  const size_t HH16_BYTES = (size_t)Ss * 32 * G4 * 16;  // 2 MiB
  const size_t IH16_OFF = HH16_OFF + HH16_BYTES;
  const size_t IH16_BYTES = (size_t)Ss * 16 * G4 * 16;  // 1 MiB
  const size_t LEN_OFF = IH16_OFF + IH16_BYTES;

  uint4* wt_hh16 = (uint4*)(ws + HH16_OFF);
  uint4* wt_ih16 = (uint4*)(ws + IH16_OFF);
  int* len = (int*)(ws + LEN_OFF);

  k_len<<<Bb, 256, 0, stream>>>(mask, len);
  k_tr<<<768, 256, 0, stream>>>(W_ih, W_hh, wt_hh16, wt_ih16);
  k_fused<<<Bb, 512, 0, stream>>>(x, wt_hh16, wt_ih16, b_ih, b_hh, len, out);
}